// Round 1
// baseline (642.737 us; speedup 1.0000x reference)
//
#include <hip/hip_runtime.h>
#include <math.h>

#define SEQ 2048
#define DIM 2048
#define NH 16
#define DH 128
#define NKV 2304   /* DIM + 2*DH : fused q|k|v projection width */
#define KOFF 2048
#define VOFF 2176
#define QK_SCALE 0.08838834764831845f

typedef _Float16 f16;
typedef _Float16 f16x8 __attribute__((ext_vector_type(8)));
typedef _Float16 f16x4 __attribute__((ext_vector_type(4)));
typedef float f32x4 __attribute__((ext_vector_type(4)));

// ---------------- RMSNorm + fp16 hi/lo split ----------------
__global__ __launch_bounds__(256) void rmsnorm_split_k(
    const float* __restrict__ x, const float* __restrict__ gamma,
    f16* __restrict__ oh, f16* __restrict__ ol)
{
    int row = blockIdx.x, tid = threadIdx.x;
    const float4* xr = (const float4*)(x + (size_t)row * DIM);
    float4 a0 = xr[tid], a1 = xr[tid + 256];
    float ss = a0.x*a0.x + a0.y*a0.y + a0.z*a0.z + a0.w*a0.w
             + a1.x*a1.x + a1.y*a1.y + a1.z*a1.z + a1.w*a1.w;
    #pragma unroll
    for (int off = 1; off < 64; off <<= 1) ss += __shfl_xor(ss, off, 64);
    __shared__ float red[4];
    if ((tid & 63) == 0) red[tid >> 6] = ss;
    __syncthreads();
    float inv = 1.0f / sqrtf((red[0] + red[1] + red[2] + red[3]) * (1.0f / DIM) + 1e-5f);
    const float4* gr = (const float4*)gamma;
    float4 g0 = gr[tid], g1 = gr[tid + 256];
    float v[8] = { a0.x*inv*g0.x, a0.y*inv*g0.y, a0.z*inv*g0.z, a0.w*inv*g0.w,
                   a1.x*inv*g1.x, a1.y*inv*g1.y, a1.z*inv*g1.z, a1.w*inv*g1.w };
    f16x4 h0, l0, h1, l1;
    #pragma unroll
    for (int i = 0; i < 4; i++) {
        f16 h = (f16)v[i];   h0[i] = h; l0[i] = (f16)(v[i]   - (float)h);
        f16 g = (f16)v[i+4]; h1[i] = g; l1[i] = (f16)(v[i+4] - (float)g);
    }
    size_t base = (size_t)row * DIM + tid * 4;
    *(f16x4*)&oh[base] = h0;  *(f16x4*)&oh[base + 1024] = h1;
    *(f16x4*)&ol[base] = l0;  *(f16x4*)&ol[base + 1024] = l1;
}

// ------------- fp32 -> transposed fp16 hi/lo (weights) -------------
template<bool WLO>
__global__ __launch_bounds__(256) void transpose_split_k(
    const float* __restrict__ in, f16* __restrict__ oh, f16* __restrict__ ol,
    int ldin, int outld)
{
    __shared__ float t[32][33];
    int tx = threadIdx.x, ty = threadIdx.y;
    int c0 = blockIdx.x * 32, r0 = blockIdx.y * 32;
    #pragma unroll
    for (int yy = 0; yy < 4; yy++)
        t[ty + yy*8][tx] = in[(size_t)(r0 + ty + yy*8) * ldin + c0 + tx];
    __syncthreads();
    #pragma unroll
    for (int yy = 0; yy < 4; yy++) {
        float v = t[tx][ty + yy*8];
        size_t o = (size_t)(c0 + ty + yy*8) * outld + r0 + tx;
        f16 h = (f16)v; oh[o] = h;
        if (WLO) ol[o] = (f16)(v - (float)h);
    }
}

// ------------- fp16 -> transposed fp16 (v slice) -------------
__global__ __launch_bounds__(256) void transpose_f16_k(
    const f16* __restrict__ in, f16* __restrict__ out, int ldin, int outld)
{
    __shared__ f16 t[32][33];
    int tx = threadIdx.x, ty = threadIdx.y;
    int c0 = blockIdx.x * 32, r0 = blockIdx.y * 32;
    #pragma unroll
    for (int yy = 0; yy < 4; yy++)
        t[ty + yy*8][tx] = in[(size_t)(r0 + ty + yy*8) * ldin + c0 + tx];
    __syncthreads();
    #pragma unroll
    for (int yy = 0; yy < 4; yy++)
        out[(size_t)(c0 + ty + yy*8) * outld + r0 + tx] = t[tx][ty + yy*8];
}

// ---------------- split-precision MFMA GEMM ----------------
// A [M][K] row-major (hi/lo fp16), Bt [N][K] row-major (hi/lo fp16).
// PASSES=3: C = Ah*Bh + Ah*Bl + Al*Bh (near-fp32).  PASSES=1: C = Ah*Bh.
// OUTMODE=0: fp32 C.  OUTMODE=1: fp16 hi/lo split C.
template<int PASSES, int OUTMODE>
__global__ __launch_bounds__(256) void gemm_k(
    const f16* __restrict__ Ah, const f16* __restrict__ Al,
    const f16* __restrict__ Bh, const f16* __restrict__ Bl,
    float* __restrict__ C, f16* __restrict__ Ch, f16* __restrict__ Cl,
    int N, int K, float scale, int scale_cols)
{
    __shared__ f16 sa_h[128][40];
    __shared__ f16 sb_h[128][40];
    __shared__ f16 sa_l[PASSES == 3 ? 128 : 1][40];
    __shared__ f16 sb_l[PASSES == 3 ? 128 : 1][40];
    int tid = threadIdx.x;
    int wave = tid >> 6, lane = tid & 63, quad = lane >> 4, l16 = lane & 15;
    int m0 = blockIdx.x * 128, n0 = blockIdx.y * 128;
    int wm = (wave & 1) * 64, wn = (wave >> 1) * 64;
    int srow = tid >> 2, sch = (tid & 3) * 8;
    f32x4 acc[4][4] = {};
    const f16* pa0 = Ah + (size_t)(m0 + srow) * K + sch;
    const f16* pa1 = Ah + (size_t)(m0 + srow + 64) * K + sch;
    const f16* pb0 = Bh + (size_t)(n0 + srow) * K + sch;
    const f16* pb1 = Bh + (size_t)(n0 + srow + 64) * K + sch;
    const f16* qa0 = Al + (size_t)(m0 + srow) * K + sch;
    const f16* qa1 = Al + (size_t)(m0 + srow + 64) * K + sch;
    const f16* qb0 = Bl + (size_t)(n0 + srow) * K + sch;
    const f16* qb1 = Bl + (size_t)(n0 + srow + 64) * K + sch;

    for (int k0 = 0; k0 < K; k0 += 32) {
        __syncthreads();
        *(f16x8*)&sa_h[srow][sch]      = *(const f16x8*)(pa0 + k0);
        *(f16x8*)&sa_h[srow + 64][sch] = *(const f16x8*)(pa1 + k0);
        *(f16x8*)&sb_h[srow][sch]      = *(const f16x8*)(pb0 + k0);
        *(f16x8*)&sb_h[srow + 64][sch] = *(const f16x8*)(pb1 + k0);
        if constexpr (PASSES == 3) {
            *(f16x8*)&sa_l[srow][sch]      = *(const f16x8*)(qa0 + k0);
            *(f16x8*)&sa_l[srow + 64][sch] = *(const f16x8*)(qa1 + k0);
            *(f16x8*)&sb_l[srow][sch]      = *(const f16x8*)(qb0 + k0);
            *(f16x8*)&sb_l[srow + 64][sch] = *(const f16x8*)(qb1 + k0);
        }
        __syncthreads();
        f16x8 ah[4], bh[4], al[4], bl[4];
        #pragma unroll
        for (int t = 0; t < 4; t++) {
            ah[t] = *(const f16x8*)&sa_h[wm + t*16 + l16][quad * 8];
            bh[t] = *(const f16x8*)&sb_h[wn + t*16 + l16][quad * 8];
        }
        if constexpr (PASSES == 3) {
            #pragma unroll
            for (int t = 0; t < 4; t++) {
                al[t] = *(const f16x8*)&sa_l[wm + t*16 + l16][quad * 8];
                bl[t] = *(const f16x8*)&sb_l[wn + t*16 + l16][quad * 8];
            }
        }
        #pragma unroll
        for (int i = 0; i < 4; i++)
            #pragma unroll
            for (int j = 0; j < 4; j++) {
                acc[i][j] = __builtin_amdgcn_mfma_f32_16x16x32_f16(ah[i], bh[j], acc[i][j], 0, 0, 0);
                if constexpr (PASSES == 3) {
                    acc[i][j] = __builtin_amdgcn_mfma_f32_16x16x32_f16(ah[i], bl[j], acc[i][j], 0, 0, 0);
                    acc[i][j] = __builtin_amdgcn_mfma_f32_16x16x32_f16(al[i], bh[j], acc[i][j], 0, 0, 0);
                }
            }
    }
    #pragma unroll
    for (int i = 0; i < 4; i++)
        #pragma unroll
        for (int j = 0; j < 4; j++) {
            int row = m0 + wm + i*16 + quad*4;
            int col = n0 + wn + j*16 + l16;
            float s = (col < scale_cols) ? scale : 1.0f;
            #pragma unroll
            for (int r = 0; r < 4; r++) {
                float v = acc[i][j][r] * s;
                if constexpr (OUTMODE == 0) {
                    C[(size_t)(row + r) * N + col] = v;
                } else {
                    f16 h = (f16)v;
                    Ch[(size_t)(row + r) * N + col] = h;
                    Cl[(size_t)(row + r) * N + col] = (f16)(v - (float)h);
                }
            }
        }
}

// ---------------- flash-style attention (faithful mask=1e-10) ----------------
// proj [SEQ][NKV]: cols 0..2047 = q (pre-scaled) hi/lo, 2048..2175 = k hi/lo, v via Vt.
// Vt [DH][SEQ] fp16. bias [NH][SEQ][SEQ] fp32. Out [SEQ][DIM] fp16.
__global__ __launch_bounds__(256) void attn_k(
    const f16* __restrict__ Ph, const f16* __restrict__ Pl,
    const f16* __restrict__ Vt, const float* __restrict__ bias,
    f16* __restrict__ Out)
{
    __shared__ f16 skh[64][136];
    __shared__ f16 skl[64][136];
    __shared__ f16 sv[128][72];
    __shared__ f16 sp[4][16][72];
    int tid = threadIdx.x, wave = tid >> 6, lane = tid & 63;
    int quad = lane >> 4, l16 = lane & 15;
    int h = blockIdx.y;
    int i0 = blockIdx.x * 64;
    int qrow = i0 + wave * 16 + l16;

    f16x8 qh[4], ql[4];
    #pragma unroll
    for (int kt = 0; kt < 4; kt++) {
        size_t off = (size_t)qrow * NKV + h * DH + kt * 32 + quad * 8;
        qh[kt] = *(const f16x8*)(Ph + off);
        ql[kt] = *(const f16x8*)(Pl + off);
    }
    f32x4 o[8];
    f32x4 zero = {0.f, 0.f, 0.f, 0.f};
    #pragma unroll
    for (int dt = 0; dt < 8; dt++) o[dt] = zero;
    float mrun[4], lrun[4];
    #pragma unroll
    for (int r = 0; r < 4; r++) { mrun[r] = -1e30f; lrun[r] = 0.f; }

    int krow = tid >> 2, kc4 = tid & 3;
    int vd = tid >> 1, vcg = tid & 1;
    const float* brow = bias + (size_t)h * SEQ * SEQ;
    int ibase = i0 + wave * 16 + quad * 4;

    for (int j0 = 0; j0 < SEQ; j0 += 64) {
        __syncthreads();
        #pragma unroll
        for (int cc = 0; cc < 4; cc++) {
            int ch = kc4 + cc * 4;
            size_t goff = (size_t)(j0 + krow) * NKV + KOFF + ch * 8;
            *(f16x8*)&skh[krow][ch * 8] = *(const f16x8*)(Ph + goff);
            *(f16x8*)&skl[krow][ch * 8] = *(const f16x8*)(Pl + goff);
        }
        #pragma unroll
        for (int cc = 0; cc < 4; cc++) {
            int ch = vcg + cc * 2;
            *(f16x8*)&sv[vd][ch * 8] = *(const f16x8*)(Vt + (size_t)vd * SEQ + j0 + ch * 8);
        }
        __syncthreads();

        f32x4 s[4];
        #pragma unroll
        for (int nt = 0; nt < 4; nt++) s[nt] = zero;
        #pragma unroll
        for (int nt = 0; nt < 4; nt++)
            #pragma unroll
            for (int kt = 0; kt < 4; kt++) {
                f16x8 kh = *(const f16x8*)&skh[nt*16 + l16][kt*32 + quad*8];
                f16x8 kl = *(const f16x8*)&skl[nt*16 + l16][kt*32 + quad*8];
                s[nt] = __builtin_amdgcn_mfma_f32_16x16x32_f16(qh[kt], kh, s[nt], 0, 0, 0);
                s[nt] = __builtin_amdgcn_mfma_f32_16x16x32_f16(qh[kt], kl, s[nt], 0, 0, 0);
                s[nt] = __builtin_amdgcn_mfma_f32_16x16x32_f16(ql[kt], kh, s[nt], 0, 0, 0);
            }
        // bias + faithful mask (masked = 1e-10, still in softmax)
        #pragma unroll
        for (int nt = 0; nt < 4; nt++) {
            int jg = j0 + nt*16 + l16;
            #pragma unroll
            for (int r = 0; r < 4; r++) {
                int ig = ibase + r;
                float v = s[nt][r] + brow[(size_t)ig * SEQ + jg];
                s[nt][r] = (jg <= ig) ? v : 1e-10f;
            }
        }
        // online softmax (state replicated across the 16 lanes of each quad)
        #pragma unroll
        for (int r = 0; r < 4; r++) {
            float mx = fmaxf(fmaxf(s[0][r], s[1][r]), fmaxf(s[2][r], s[3][r]));
            mx = fmaxf(mx, __shfl_xor(mx, 1, 64));
            mx = fmaxf(mx, __shfl_xor(mx, 2, 64));
            mx = fmaxf(mx, __shfl_xor(mx, 4, 64));
            mx = fmaxf(mx, __shfl_xor(mx, 8, 64));
            float mn = fmaxf(mrun[r], mx);
            float alpha = __expf(mrun[r] - mn);
            mrun[r] = mn;
            float rs = 0.f;
            #pragma unroll
            for (int nt = 0; nt < 4; nt++) {
                float p = __expf(s[nt][r] - mn);
                s[nt][r] = p; rs += p;
            }
            rs += __shfl_xor(rs, 1, 64);
            rs += __shfl_xor(rs, 2, 64);
            rs += __shfl_xor(rs, 4, 64);
            rs += __shfl_xor(rs, 8, 64);
            lrun[r] = lrun[r] * alpha + rs;
            #pragma unroll
            for (int dt = 0; dt < 8; dt++) o[dt][r] *= alpha;
            #pragma unroll
            for (int nt = 0; nt < 4; nt++)
                sp[wave][quad*4 + r][nt*16 + l16] = (f16)s[nt][r];
        }
        // PV: P (C-layout -> LDS -> A-layout), Vt tile as B
        #pragma unroll
        for (int ks = 0; ks < 2; ks++) {
            f16x8 pa = *(const f16x8*)&sp[wave][l16][ks*32 + quad*8];
            #pragma unroll
            for (int dt = 0; dt < 8; dt++) {
                f16x8 vb = *(const f16x8*)&sv[dt*16 + l16][ks*32 + quad*8];
                o[dt] = __builtin_amdgcn_mfma_f32_16x16x32_f16(pa, vb, o[dt], 0, 0, 0);
            }
        }
    }
    #pragma unroll
    for (int dt = 0; dt < 8; dt++) {
        int col = h * DH + dt*16 + l16;
        #pragma unroll
        for (int r = 0; r < 4; r++) {
            int ig = i0 + wave*16 + quad*4 + r;
            Out[(size_t)ig * DIM + col] = (f16)(o[dt][r] / lrun[r]);
        }
    }
}

// ---------------- host orchestration ----------------
extern "C" void kernel_launch(void* const* d_in, const int* in_sizes, int n_in,
                              void* d_out, int out_size, void* d_ws, size_t ws_size,
                              hipStream_t stream)
{
    const float* x     = (const float*)d_in[0];
    const float* bias  = (const float*)d_in[1];
    const float* gamma = (const float*)d_in[2];
    const float* wq    = (const float*)d_in[3];
    const float* wk    = (const float*)d_in[4];
    const float* wv    = (const float*)d_in[5];
    const float* wo    = (const float*)d_in[6];
    float* out = (float*)d_out;
    char* ws = (char*)d_ws;

    const size_t MB = 1024 * 1024;
    f16* xn_h   = (f16*)(ws);              // 8 MB   (later reused as attn_o)
    f16* xn_l   = (f16*)(ws + 8  * MB);    // 8 MB   (later reused as vT)
    f16* wT_h   = (f16*)(ws + 16 * MB);    // 9 MB  [NKV][DIM]
    f16* wT_l   = (f16*)(ws + 25 * MB);    // 9 MB
    f16* woT_h  = (f16*)(ws + 34 * MB);    // 8 MB  [DIM][DIM]
    f16* proj_h = (f16*)(ws + 42 * MB);    // 9 MB  [SEQ][NKV]
    f16* proj_l = (f16*)(ws + 51 * MB);    // 9 MB   -> 60 MB total
    f16* attn_o = xn_h;                    // [SEQ][DIM], xn dead by then
    f16* vT     = xn_l;                    // [DH][SEQ]

    dim3 tb(32, 8);

    rmsnorm_split_k<<<SEQ, 256, 0, stream>>>(x, gamma, xn_h, xn_l);

    transpose_split_k<true><<<dim3(64, 64), tb, 0, stream>>>(wq, wT_h, wT_l, DIM, DIM);
    transpose_split_k<true><<<dim3(4, 64),  tb, 0, stream>>>(wk, wT_h + (size_t)KOFF * DIM,
                                                             wT_l + (size_t)KOFF * DIM, DH, DIM);
    transpose_split_k<true><<<dim3(4, 64),  tb, 0, stream>>>(wv, wT_h + (size_t)VOFF * DIM,
                                                             wT_l + (size_t)VOFF * DIM, DH, DIM);
    transpose_split_k<false><<<dim3(64, 64), tb, 0, stream>>>(wo, woT_h, nullptr, DIM, DIM);

    // fused q|k|v projection, q columns pre-scaled by 1/sqrt(dh), near-fp32 via 3-pass
    gemm_k<3, 1><<<dim3(16, 18), 256, 0, stream>>>(xn_h, xn_l, wT_h, wT_l,
                                                   nullptr, proj_h, proj_l,
                                                   NKV, DIM, QK_SCALE, DIM);

    // v slice -> Vt [DH][SEQ]
    transpose_f16_k<<<dim3(4, 64), tb, 0, stream>>>(proj_h + VOFF, vT, NKV, SEQ);

    attn_k<<<dim3(32, 16), 256, 0, stream>>>(proj_h, proj_l, vT, bias, attn_o);

    // out = attn_o @ wo  (plain fp16 single pass is accurate enough here)
    gemm_k<1, 0><<<dim3(16, 16), 256, 0, stream>>>(attn_o, attn_o, woT_h, woT_h,
                                                   out, nullptr, nullptr,
                                                   DIM, DIM, 1.0f, 0);
}